// Round 1
// baseline (1244.418 us; speedup 1.0000x reference)
//
#include <hip/hip_runtime.h>
#include <stdint.h>
#include <stddef.h>

// Problem constants (from reference): B=16, S=512, D=256, L=8192, DROP_P=0.2
#define B_ 16
#define S_ 512
#define D_ 256
#define L_ 8192

#define TILE 64
#define KT 32
#define LDP (TILE + 4)  // LDS row stride: 68 floats, keeps float4 alignment (272B)

// ---------------------------------------------------------------------------
// JAX threefry2x32, key = jax.random.key(42) -> (k0,k1) = (0,42), 20 rounds.
// Partitionable random_bits (JAX >= 0.4.30 default): for flat index j (< 2^32):
//   (o0,o1) = threefry2x32((0,42), (0, j)); bits = o0 ^ o1
//   u = bitcast((bits>>9)|0x3f800000) - 1.0f ; keep = u < 0.8f
// ---------------------------------------------------------------------------
__device__ __forceinline__ uint32_t rotl32(uint32_t x, int r) {
  return (x << r) | (x >> (32 - r));
}

__device__ __forceinline__ void threefry_0_42(uint32_t x0, uint32_t x1,
                                              uint32_t& o0, uint32_t& o1) {
  const uint32_t k0 = 0u;
  const uint32_t k1 = 42u;
  const uint32_t k2 = 0x1BD11BDAu ^ k0 ^ k1;
  uint32_t v0 = x0 + k0;
  uint32_t v1 = x1 + k1;
#define TF_R(r) { v0 += v1; v1 = rotl32(v1, (r)); v1 ^= v0; }
  TF_R(13) TF_R(15) TF_R(26) TF_R(6)
  v0 += k1; v1 += k2 + 1u;
  TF_R(17) TF_R(29) TF_R(16) TF_R(24)
  v0 += k2; v1 += k0 + 2u;
  TF_R(13) TF_R(15) TF_R(26) TF_R(6)
  v0 += k0; v1 += k1 + 3u;
  TF_R(17) TF_R(29) TF_R(16) TF_R(24)
  v0 += k1; v1 += k2 + 4u;
  TF_R(13) TF_R(15) TF_R(26) TF_R(6)
  v0 += k2; v1 += k0 + 5u;
#undef TF_R
  o0 = v0; o1 = v1;
}

__device__ __forceinline__ bool drop_keep(uint32_t j) {
  uint32_t o0, o1;
  threefry_0_42(0u, j, o0, o1);
  uint32_t bits = o0 ^ o1;
  float u = __uint_as_float((bits >> 9) | 0x3f800000u) - 1.0f;
  return u < 0.8f;
}

// ---------------------------------------------------------------------------
// Reductions (wave = 64)
// ---------------------------------------------------------------------------
__device__ __forceinline__ float waveReduceMax(float v) {
#pragma unroll
  for (int o = 32; o > 0; o >>= 1) v = fmaxf(v, __shfl_down(v, o, 64));
  return v;
}
__device__ __forceinline__ float waveReduceSum(float v) {
#pragma unroll
  for (int o = 32; o > 0; o >>= 1) v += __shfl_down(v, o, 64);
  return v;
}

// ---------------------------------------------------------------------------
// GEMM1: scores[b, st..st+63 (chunk-local), lt..lt+63] = x[b,s,:] . E[b,l,:]
// 64x64 tile, K=256, fp32.  LDS layout [k][m] so inner loop does float4 reads.
// ---------------------------------------------------------------------------
__global__ __launch_bounds__(256)
void gemm1_kernel(const float* __restrict__ x, const float* __restrict__ E,
                  float* __restrict__ scores, int s0, int s_chunk) {
  const int b = blockIdx.z;
  const int lt = blockIdx.x * TILE;
  const int st = blockIdx.y * TILE;
  const int tid = threadIdx.x;
  const int tx = tid & 15;   // label sub-tile
  const int ty = tid >> 4;   // token sub-tile

  __shared__ float As[KT][LDP];  // [k][token]
  __shared__ float Bs[KT][LDP];  // [k][label]

  const int lrow = tid >> 2;        // 0..63
  const int lcol = (tid & 3) * 8;   // 0,8,16,24

  const float* xp = x + ((size_t)b * S_ + (size_t)(s0 + st + lrow)) * D_ + lcol;
  const float* ep = E + ((size_t)b * L_ + (size_t)(lt + lrow)) * D_ + lcol;

  float acc[4][4] = {{0.f, 0.f, 0.f, 0.f}, {0.f, 0.f, 0.f, 0.f},
                     {0.f, 0.f, 0.f, 0.f}, {0.f, 0.f, 0.f, 0.f}};

  for (int k0 = 0; k0 < D_; k0 += KT) {
    float4 a0 = *(const float4*)(xp + k0);
    float4 a1 = *(const float4*)(xp + k0 + 4);
    float4 b0 = *(const float4*)(ep + k0);
    float4 b1 = *(const float4*)(ep + k0 + 4);
    __syncthreads();
    As[lcol + 0][lrow] = a0.x; As[lcol + 1][lrow] = a0.y;
    As[lcol + 2][lrow] = a0.z; As[lcol + 3][lrow] = a0.w;
    As[lcol + 4][lrow] = a1.x; As[lcol + 5][lrow] = a1.y;
    As[lcol + 6][lrow] = a1.z; As[lcol + 7][lrow] = a1.w;
    Bs[lcol + 0][lrow] = b0.x; Bs[lcol + 1][lrow] = b0.y;
    Bs[lcol + 2][lrow] = b0.z; Bs[lcol + 3][lrow] = b0.w;
    Bs[lcol + 4][lrow] = b1.x; Bs[lcol + 5][lrow] = b1.y;
    Bs[lcol + 6][lrow] = b1.z; Bs[lcol + 7][lrow] = b1.w;
    __syncthreads();
#pragma unroll
    for (int kk = 0; kk < KT; ++kk) {
      float4 av = *(const float4*)&As[kk][ty * 4];
      float4 bv = *(const float4*)&Bs[kk][tx * 4];
      float a[4] = {av.x, av.y, av.z, av.w};
      float bb[4] = {bv.x, bv.y, bv.z, bv.w};
#pragma unroll
      for (int i = 0; i < 4; ++i)
#pragma unroll
        for (int j = 0; j < 4; ++j) acc[i][j] = fmaf(a[i], bb[j], acc[i][j]);
    }
  }

  float* sp = scores + ((size_t)b * s_chunk + (size_t)(st + ty * 4)) * L_ + lt + tx * 4;
#pragma unroll
  for (int i = 0; i < 4; ++i) {
    float4 o = make_float4(acc[i][0], acc[i][1], acc[i][2], acc[i][3]);
    *(float4*)(sp + (size_t)i * L_) = o;
  }
}

// ---------------------------------------------------------------------------
// Softmax over L per token + post-softmax mask + exact JAX dropout, in-place.
// One block (256 thr) per token; 32 elements/thread, stride-256 (coalesced).
// ---------------------------------------------------------------------------
__global__ __launch_bounds__(256)
void softmax_drop_kernel(float* __restrict__ probs, const int* __restrict__ mask,
                         int s0, int s_chunk) {
  const int token = blockIdx.x;  // b * s_chunk + si
  const int b = token / s_chunk;
  const int si = token - b * s_chunk;
  const int s = s0 + si;
  float* row = probs + (size_t)token * L_;
  const int tid = threadIdx.x;
  const int lane = tid & 63;
  const int wid = tid >> 6;
  __shared__ float red[4];

  float v[32];
  float m = -3.402823466e38f;
#pragma unroll
  for (int k = 0; k < 32; ++k) {
    v[k] = row[tid + 256 * k];
    m = fmaxf(m, v[k]);
  }
  m = waveReduceMax(m);
  if (lane == 0) red[wid] = m;
  __syncthreads();
  m = fmaxf(fmaxf(red[0], red[1]), fmaxf(red[2], red[3]));
  __syncthreads();  // protect red before reuse

  float sum = 0.f;
#pragma unroll
  for (int k = 0; k < 32; ++k) {
    v[k] = expf(v[k] - m);
    sum += v[k];
  }
  sum = waveReduceSum(sum);
  if (lane == 0) red[wid] = sum;
  __syncthreads();
  sum = red[0] + red[1] + red[2] + red[3];

  const float mval = (mask[b * S_ + s] != 0) ? 1.0f : 0.0f;
  const float factor = mval * (1.25f / sum);  // 1/(1-p) fused with 1/Z
  const uint32_t base = (uint32_t)(b * S_ + s) * (uint32_t)L_;
#pragma unroll 4
  for (int k = 0; k < 32; ++k) {
    uint32_t l = (uint32_t)tid + 256u * (uint32_t)k;
    bool keep = drop_keep(base + l);
    row[l] = keep ? v[k] * factor : 0.0f;
  }
}

// ---------------------------------------------------------------------------
// GEMM2: out[b, lt.., dt..] (+)= sum_s probs[b,s,l] * x[b,s,d]
// K = s_chunk. chunk 0 stores, later chunks accumulate.
// ---------------------------------------------------------------------------
__global__ __launch_bounds__(256)
void gemm2_kernel(const float* __restrict__ probs, const float* __restrict__ x,
                  float* __restrict__ out, int s0, int s_chunk, int first) {
  const int b = blockIdx.z;
  const int dt = blockIdx.x * TILE;
  const int lt = blockIdx.y * TILE;
  const int tid = threadIdx.x;
  const int tx = tid & 15;  // d sub-tile
  const int ty = tid >> 4;  // label sub-tile

  __shared__ float Ps[KT][LDP];  // [s][label]
  __shared__ float Xs[KT][LDP];  // [s][d]

  const int lrow = tid >> 3;       // 0..31 (s within k-tile)
  const int lcol = (tid & 7) * 8;  // 0..56

  const float* pp = probs + ((size_t)b * s_chunk + (size_t)lrow) * L_ + lt + lcol;
  const float* xp = x + ((size_t)b * S_ + (size_t)(s0 + lrow)) * D_ + dt + lcol;

  float acc[4][4] = {{0.f, 0.f, 0.f, 0.f}, {0.f, 0.f, 0.f, 0.f},
                     {0.f, 0.f, 0.f, 0.f}, {0.f, 0.f, 0.f, 0.f}};

  for (int k0 = 0; k0 < s_chunk; k0 += KT) {
    float4 p0 = *(const float4*)(pp);
    float4 p1 = *(const float4*)(pp + 4);
    float4 q0 = *(const float4*)(xp);
    float4 q1 = *(const float4*)(xp + 4);
    pp += (size_t)KT * L_;
    xp += (size_t)KT * D_;
    __syncthreads();
    *(float4*)&Ps[lrow][lcol] = p0;
    *(float4*)&Ps[lrow][lcol + 4] = p1;
    *(float4*)&Xs[lrow][lcol] = q0;
    *(float4*)&Xs[lrow][lcol + 4] = q1;
    __syncthreads();
#pragma unroll
    for (int kk = 0; kk < KT; ++kk) {
      float4 av = *(const float4*)&Ps[kk][ty * 4];
      float4 bv = *(const float4*)&Xs[kk][tx * 4];
      float a[4] = {av.x, av.y, av.z, av.w};
      float bb[4] = {bv.x, bv.y, bv.z, bv.w};
#pragma unroll
      for (int i = 0; i < 4; ++i)
#pragma unroll
        for (int j = 0; j < 4; ++j) acc[i][j] = fmaf(a[i], bb[j], acc[i][j]);
    }
  }

  float* op = out + ((size_t)b * L_ + (size_t)(lt + ty * 4)) * D_ + dt + tx * 4;
#pragma unroll
  for (int i = 0; i < 4; ++i) {
    float4 o = make_float4(acc[i][0], acc[i][1], acc[i][2], acc[i][3]);
    if (!first) {
      float4 prev = *(float4*)(op + (size_t)i * D_);
      o.x += prev.x; o.y += prev.y; o.z += prev.z; o.w += prev.w;
    }
    *(float4*)(op + (size_t)i * D_) = o;
  }
}

// ---------------------------------------------------------------------------
extern "C" void kernel_launch(void* const* d_in, const int* in_sizes, int n_in,
                              void* d_out, int out_size, void* d_ws, size_t ws_size,
                              hipStream_t stream) {
  const float* x = (const float*)d_in[0];        // [B,S,D] fp32
  const int* mask = (const int*)d_in[1];         // [B,S] bool->int32
  const float* E = (const float*)d_in[2];        // [B,L,D] fp32
  float* out = (float*)d_out;                    // [B,L,D] fp32
  float* probs = (float*)d_ws;                   // [B, s_chunk, L] fp32 scratch

  // Largest power-of-two S-chunk whose probs buffer fits in ws.
  int s_chunk = S_;
  while ((size_t)B_ * (size_t)s_chunk * (size_t)L_ * sizeof(float) > ws_size &&
         s_chunk > TILE)
    s_chunk >>= 1;
  const int nch = S_ / s_chunk;

  for (int c = 0; c < nch; ++c) {
    const int s0 = c * s_chunk;
    dim3 g1(L_ / TILE, s_chunk / TILE, B_);
    gemm1_kernel<<<g1, 256, 0, stream>>>(x, E, probs, s0, s_chunk);
    softmax_drop_kernel<<<dim3(B_ * s_chunk), 256, 0, stream>>>(probs, mask, s0,
                                                                s_chunk);
    dim3 g2(D_ / TILE, L_ / TILE, B_);
    gemm2_kernel<<<g2, 256, 0, stream>>>(probs, x, out, s0, s_chunk, c == 0);
  }
}

// Round 2
// 733.140 us; speedup vs baseline: 1.6974x; 1.6974x over previous
//
#include <hip/hip_runtime.h>
#include <stdint.h>
#include <stddef.h>

// B=16, S=512, D=256, L=8192, DROP_P=0.2
#define B_ 16
#define S_ 512
#define D_ 256
#define L_ 8192
#define SC 128            // token chunk for scores buffer (gemm1 M-tile = 128)

typedef unsigned short u16;
typedef u16 u16x4v __attribute__((ext_vector_type(4)));
typedef u16 u16x8v __attribute__((ext_vector_type(8)));
typedef short bf16x8 __attribute__((ext_vector_type(8)));   // MFMA A/B frag (8 bf16)
typedef float f32x4 __attribute__((ext_vector_type(4)));    // MFMA C/D frag

// ---------------------------------------------------------------------------
// async global -> LDS, 16B per lane (m97 path). LDS dest = wave base + lane*16.
// ---------------------------------------------------------------------------
__device__ __forceinline__ void gl16(const void* g, void* l) {
  __builtin_amdgcn_global_load_lds(
      (const __attribute__((address_space(1))) unsigned int*)g,
      (__attribute__((address_space(3))) unsigned int*)l, 16, 0, 0);
}

// ---------------------------------------------------------------------------
// bf16 helpers (RNE)
// ---------------------------------------------------------------------------
__device__ __forceinline__ u16 f32_to_bf16(float f) {
  uint32_t u = __float_as_uint(f);
  u = (u + 0x7FFFu + ((u >> 16) & 1u)) >> 16;
  return (u16)u;
}
__device__ __forceinline__ float bf16_to_f32(u16 h) {
  return __uint_as_float(((uint32_t)h) << 16);
}

// ---------------------------------------------------------------------------
// JAX threefry2x32 dropout, key=(0,42), partitionable bits (verified round 1)
// ---------------------------------------------------------------------------
__device__ __forceinline__ uint32_t rotl32(uint32_t x, int r) {
  return (x << r) | (x >> (32 - r));
}
__device__ __forceinline__ bool drop_keep(uint32_t j) {
  const uint32_t k0 = 0u, k1 = 42u, k2 = 0x1BD11BDAu ^ k0 ^ k1;
  uint32_t v0 = 0u + k0;
  uint32_t v1 = j + k1;
#define TF_R(r) { v0 += v1; v1 = rotl32(v1, (r)); v1 ^= v0; }
  TF_R(13) TF_R(15) TF_R(26) TF_R(6)
  v0 += k1; v1 += k2 + 1u;
  TF_R(17) TF_R(29) TF_R(16) TF_R(24)
  v0 += k2; v1 += k0 + 2u;
  TF_R(13) TF_R(15) TF_R(26) TF_R(6)
  v0 += k0; v1 += k1 + 3u;
  TF_R(17) TF_R(29) TF_R(16) TF_R(24)
  v0 += k1; v1 += k2 + 4u;
  TF_R(13) TF_R(15) TF_R(26) TF_R(6)
  v0 += k2; v1 += k0 + 5u;
#undef TF_R
  uint32_t bits = v0 ^ v1;
  float u = __uint_as_float((bits >> 9) | 0x3f800000u) - 1.0f;
  return u < 0.8f;
}

__device__ __forceinline__ float waveReduceMax(float v) {
#pragma unroll
  for (int o = 32; o > 0; o >>= 1) v = fmaxf(v, __shfl_down(v, o, 64));
  return v;
}
__device__ __forceinline__ float waveReduceSum(float v) {
#pragma unroll
  for (int o = 32; o > 0; o >>= 1) v += __shfl_down(v, o, 64);
  return v;
}

// ---------------------------------------------------------------------------
// prep: fp32 -> (hi, lo) bf16 split, 4 floats/thread
// ---------------------------------------------------------------------------
__global__ __launch_bounds__(256)
void split_kernel(const float* __restrict__ src, u16* __restrict__ hi,
                  u16* __restrict__ lo, int n) {
  int i = (blockIdx.x * 256 + threadIdx.x) * 4;
  if (i >= n) return;
  float4 v = *(const float4*)&src[i];
  u16x4v h, l;
  float f[4] = {v.x, v.y, v.z, v.w};
#pragma unroll
  for (int j = 0; j < 4; ++j) {
    u16 hh = f32_to_bf16(f[j]);
    h[j] = hh;
    l[j] = f32_to_bf16(f[j] - bf16_to_f32(hh));
  }
  *(u16x4v*)&hi[i] = h;
  *(u16x4v*)&lo[i] = l;
}

// x [B][S][D] fp32 -> xT [B][D][S] bf16 (single precision operand for GEMM2)
__global__ __launch_bounds__(256)
void xt_kernel(const float* __restrict__ x, u16* __restrict__ xT) {
  const int b = blockIdx.z, sb = blockIdx.x * 32, db = blockIdx.y * 32;
  __shared__ float t[32][33];
  const int tid = threadIdx.x;
  const int r = tid >> 3, c4 = (tid & 7) * 4;
  float4 v = *(const float4*)&x[((size_t)b * S_ + sb + r) * D_ + db + c4];
  t[r][c4] = v.x; t[r][c4 + 1] = v.y; t[r][c4 + 2] = v.z; t[r][c4 + 3] = v.w;
  __syncthreads();
  const int dr = tid >> 3, s4 = (tid & 7) * 4;
  u16x4v o;
#pragma unroll
  for (int j = 0; j < 4; ++j) o[j] = f32_to_bf16(t[s4 + j][dr]);
  *(u16x4v*)&xT[((size_t)b * D_ + db + dr) * S_ + sb + s4] = o;
}

// ---------------------------------------------------------------------------
// GEMM1 (split bf16 MFMA, NT): scores[b, 0..127, lt..lt+127] fp32
//   = (xh+xl)[s,:] . (eh+el)[l,:]  (hi*hi + hi*lo + lo*hi)
// 128x128 tile, BK=32, 256 thr = 4 waves of 64x64 (4x4 MFMA 16x16x32).
// ---------------------------------------------------------------------------
__global__ __launch_bounds__(256)
void gemm1_mfma(const u16* __restrict__ xh, const u16* __restrict__ xl,
                const u16* __restrict__ eh, const u16* __restrict__ el,
                float* __restrict__ scores, int s0) {
  __shared__ __align__(16) u16 Ah[128 * 32];
  __shared__ __align__(16) u16 Al[128 * 32];
  __shared__ __align__(16) u16 Bh[128 * 32];
  __shared__ __align__(16) u16 Bl[128 * 32];

  const int tid = threadIdx.x;
  const int lane = tid & 63, wave = tid >> 6;
  const int b = blockIdx.z, lt = blockIdx.x * 128;

  // staging map: instr (wave,i): rows [wave*32+i*16, +16), lane covers
  // row = +lane/4, kcol = (lane&3)*8 ; LDS off = (wave*2+i)*1024 + lane*16 B
  const int ra = wave * 32 + (lane >> 2);
  const int kc = (lane & 3) * 8;
  const size_t offA0 = ((size_t)b * S_ + s0 + ra) * D_ + kc;
  const size_t offA1 = offA0 + 16 * D_;
  const size_t offB0 = ((size_t)b * L_ + lt + ra) * D_ + kc;
  const size_t offB1 = offB0 + 16 * D_;
  const int lo0 = wave * 2048 + lane * 16;  // bytes

  const int lm = lane & 15, kq = lane >> 4;
  const int wm = (wave & 1) * 64, wn = (wave >> 1) * 64;

  f32x4 acc[4][4] = {};

  for (int k0 = 0; k0 < D_; k0 += 32) {
    __syncthreads();
    gl16(xh + offA0 + k0, (char*)Ah + lo0);
    gl16(xh + offA1 + k0, (char*)Ah + lo0 + 1024);
    gl16(xl + offA0 + k0, (char*)Al + lo0);
    gl16(xl + offA1 + k0, (char*)Al + lo0 + 1024);
    gl16(eh + offB0 + k0, (char*)Bh + lo0);
    gl16(eh + offB1 + k0, (char*)Bh + lo0 + 1024);
    gl16(el + offB0 + k0, (char*)Bl + lo0);
    gl16(el + offB1 + k0, (char*)Bl + lo0 + 1024);
    __syncthreads();

    bf16x8 fah[4], fal[4], fbh[4], fbl[4];
#pragma unroll
    for (int mi = 0; mi < 4; ++mi) {
      int idx = (wm + mi * 16 + lm) * 32 + kq * 8;
      fah[mi] = *(const bf16x8*)&Ah[idx];
      fal[mi] = *(const bf16x8*)&Al[idx];
    }
#pragma unroll
    for (int ni = 0; ni < 4; ++ni) {
      int idx = (wn + ni * 16 + lm) * 32 + kq * 8;
      fbh[ni] = *(const bf16x8*)&Bh[idx];
      fbl[ni] = *(const bf16x8*)&Bl[idx];
    }
#pragma unroll
    for (int mi = 0; mi < 4; ++mi)
#pragma unroll
      for (int ni = 0; ni < 4; ++ni) {
        acc[mi][ni] = __builtin_amdgcn_mfma_f32_16x16x32_bf16(
            fah[mi], fbh[ni], acc[mi][ni], 0, 0, 0);
        acc[mi][ni] = __builtin_amdgcn_mfma_f32_16x16x32_bf16(
            fah[mi], fbl[ni], acc[mi][ni], 0, 0, 0);
        acc[mi][ni] = __builtin_amdgcn_mfma_f32_16x16x32_bf16(
            fal[mi], fbh[ni], acc[mi][ni], 0, 0, 0);
      }
  }

  // C/D: col = lane&15 (n), row = (lane>>4)*4 + reg (m)
#pragma unroll
  for (int mi = 0; mi < 4; ++mi)
#pragma unroll
    for (int ni = 0; ni < 4; ++ni) {
      const int m0 = wm + mi * 16 + kq * 4;
      const int n = wn + ni * 16 + lm;
      float* sp = scores + ((size_t)b * SC + m0) * L_ + lt + n;
#pragma unroll
      for (int r = 0; r < 4; ++r) sp[(size_t)r * L_] = acc[mi][ni][r];
    }
}

// ---------------------------------------------------------------------------
// per-token row stats: m, factor = mask ? 1.25/Z : 0
// ---------------------------------------------------------------------------
__global__ __launch_bounds__(256)
void stats_kernel(const float* __restrict__ scores, const int* __restrict__ mask,
                  float2* __restrict__ stats, int s0) {
  const int token = blockIdx.x;  // b*SC + si
  const int b = token >> 7, si = token & 127;
  const float* row = scores + (size_t)token * L_;
  const int tid = threadIdx.x, lane = tid & 63, wid = tid >> 6;
  __shared__ float red[4];

  float v[32];
  float m = -3.402823466e38f;
#pragma unroll
  for (int k = 0; k < 32; ++k) {
    v[k] = row[tid + 256 * k];
    m = fmaxf(m, v[k]);
  }
  m = waveReduceMax(m);
  if (lane == 0) red[wid] = m;
  __syncthreads();
  m = fmaxf(fmaxf(red[0], red[1]), fmaxf(red[2], red[3]));
  __syncthreads();

  float sum = 0.f;
#pragma unroll
  for (int k = 0; k < 32; ++k) sum += expf(v[k] - m);
  sum = waveReduceSum(sum);
  if (lane == 0) red[wid] = sum;
  __syncthreads();
  if (tid == 0) {
    float Z = red[0] + red[1] + red[2] + red[3];
    float f = (mask[b * S_ + s0 + si] != 0) ? (1.25f / Z) : 0.0f;
    stats[token] = make_float2(m, f);
  }
}

// ---------------------------------------------------------------------------
// transpose + softmax-normalize + dropout: scores fp32 [b][sc][L] ->
// probsT bf16 [b][L][*] at s-offset kofs (row stride ks)
// ---------------------------------------------------------------------------
__global__ __launch_bounds__(256)
void tdrop_kernel(const float* __restrict__ scores, const float2* __restrict__ stats,
                  u16* __restrict__ probsT, int s0, int ks, int kofs) {
  const int b = blockIdx.z, lt = blockIdx.x * 64, st = blockIdx.y * 64;
  const int tid = threadIdx.x;
  __shared__ float T[64][65];

  const int r0 = tid >> 4, c0 = (tid & 15) * 4;
#pragma unroll
  for (int p = 0; p < 4; ++p) {
    int r = p * 16 + r0;
    float4 v = *(const float4*)&scores[((size_t)b * SC + st + r) * L_ + lt + c0];
    T[r][c0] = v.x; T[r][c0 + 1] = v.y; T[r][c0 + 2] = v.z; T[r][c0 + 3] = v.w;
  }
  __syncthreads();

  const int sb = (tid & 7) * 8;
#pragma unroll
  for (int p = 0; p < 2; ++p) {
    int ll = p * 32 + (tid >> 3);
    u16x8v o;
#pragma unroll
    for (int j = 0; j < 8; ++j) {
      int s_loc = st + sb + j;
      float2 mf = stats[b * SC + s_loc];
      float pv = expf(T[sb + j][ll] - mf.x) * mf.y;
      uint32_t gidx =
          ((uint32_t)(b * S_ + s0 + s_loc)) * (uint32_t)L_ + (uint32_t)(lt + ll);
      o[j] = drop_keep(gidx) ? f32_to_bf16(pv) : (u16)0;
    }
    *(u16x8v*)&probsT[((size_t)b * L_ + lt + ll) * (size_t)ks + kofs + st + sb] = o;
  }
}

// ---------------------------------------------------------------------------
// GEMM2 (bf16 MFMA, NT): out[b, lt..+127, dt..+127] (+)= probsT[l,:] . xT[d,:]
// K = ks (512 plan A / 128 plan C)
// ---------------------------------------------------------------------------
__global__ __launch_bounds__(256)
void gemm2_mfma(const u16* __restrict__ pT, const u16* __restrict__ xT,
                float* __restrict__ out, int K, int ks, int s0, int accum) {
  __shared__ __align__(16) u16 As[128 * 32];
  __shared__ __align__(16) u16 Bs[128 * 32];

  const int tid = threadIdx.x;
  const int lane = tid & 63, wave = tid >> 6;
  const int b = blockIdx.z, lt = blockIdx.x * 128, dt = blockIdx.y * 128;

  const int ra = wave * 32 + (lane >> 2);
  const int kc = (lane & 3) * 8;
  const size_t offA0 = ((size_t)b * L_ + lt + ra) * (size_t)ks + s0 + kc;
  const size_t offA1 = offA0 + (size_t)16 * ks;
  const size_t offB0 = ((size_t)b * D_ + dt + ra) * S_ + s0 + kc;
  const size_t offB1 = offB0 + 16 * S_;
  const int lo0 = wave * 2048 + lane * 16;

  const int lm = lane & 15, kq = lane >> 4;
  const int wm = (wave & 1) * 64, wn = (wave >> 1) * 64;

  f32x4 acc[4][4] = {};

  for (int k0 = 0; k0 < K; k0 += 32) {
    __syncthreads();
    gl16(pT + offA0 + k0, (char*)As + lo0);
    gl16(pT + offA1 + k0, (char*)As + lo0 + 1024);
    gl16(xT + offB0 + k0, (char*)Bs + lo0);
    gl16(xT + offB1 + k0, (char*)Bs + lo0 + 1024);
    __syncthreads();

    bf16x8 fa[4], fb[4];
#pragma unroll
    for (int mi = 0; mi < 4; ++mi)
      fa[mi] = *(const bf16x8*)&As[(wm + mi * 16 + lm) * 32 + kq * 8];
#pragma unroll
    for (int ni = 0; ni < 4; ++ni)
      fb[ni] = *(const bf16x8*)&Bs[(wn + ni * 16 + lm) * 32 + kq * 8];
#pragma unroll
    for (int mi = 0; mi < 4; ++mi)
#pragma unroll
      for (int ni = 0; ni < 4; ++ni)
        acc[mi][ni] = __builtin_amdgcn_mfma_f32_16x16x32_bf16(
            fa[mi], fb[ni], acc[mi][ni], 0, 0, 0);
  }

#pragma unroll
  for (int mi = 0; mi < 4; ++mi)
#pragma unroll
    for (int ni = 0; ni < 4; ++ni) {
      const int m0 = wm + mi * 16 + kq * 4;
      const int n = wn + ni * 16 + lm;
      float* op = out + ((size_t)b * L_ + lt + m0) * D_ + dt + n;
#pragma unroll
      for (int r = 0; r < 4; ++r) {
        float val = acc[mi][ni][r];
        if (accum) val += op[(size_t)r * D_];
        op[(size_t)r * D_] = val;
      }
    }
}

// ---------------------------------------------------------------------------
extern "C" void kernel_launch(void* const* d_in, const int* in_sizes, int n_in,
                              void* d_out, int out_size, void* d_ws, size_t ws_size,
                              hipStream_t stream) {
  const float* x = (const float*)d_in[0];
  const int* mask = (const int*)d_in[1];
  const float* E = (const float*)d_in[2];
  float* out = (float*)d_out;

  char* ws = (char*)d_ws;
  const size_t nE = (size_t)B_ * L_ * D_;     // 33.5M
  const size_t nX = (size_t)B_ * S_ * D_;     // 2.1M
  size_t o = 0;
  u16* Eh = (u16*)(ws + o); o += nE * 2;      // 64 MB
  u16* El = (u16*)(ws + o); o += nE * 2;      // 64 MB
  u16* Xh = (u16*)(ws + o); o += nX * 2;      // 4 MB
  u16* Xl = (u16*)(ws + o); o += nX * 2;      // 4 MB
  u16* XT = (u16*)(ws + o); o += nX * 2;      // 4 MB
  float2* stats = (float2*)(ws + o); o += 131072;
  float* scores = (float*)(ws + o); o += (size_t)B_ * SC * L_ * 4;  // 67 MB
  u16* probsT = (u16*)(ws + o);
  const size_t fixed = o;
  const size_t needA = fixed + (size_t)B_ * L_ * S_ * 2;   // + 134 MB = ~348 MB
  const size_t needC = fixed + (size_t)B_ * L_ * SC * 2;   // +  33 MB = ~248 MB
  const int planA = (ws_size >= needA) ? 1 : 0;
  (void)needC;

  // prep
  split_kernel<<<dim3((nE / 4 + 255) / 256), 256, 0, stream>>>(E, Eh, El, (int)nE);
  split_kernel<<<dim3((nX / 4 + 255) / 256), 256, 0, stream>>>(x, Xh, Xl, (int)nX);
  xt_kernel<<<dim3(S_ / 32, D_ / 32, B_), 256, 0, stream>>>(x, XT);

  const int nch = S_ / SC;
  for (int c = 0; c < nch; ++c) {
    const int s0 = c * SC;
    gemm1_mfma<<<dim3(L_ / 128, 1, B_), 256, 0, stream>>>(Xh, Xl, Eh, El, scores, s0);
    stats_kernel<<<dim3(B_ * SC), 256, 0, stream>>>(scores, mask, stats, s0);
    if (planA) {
      tdrop_kernel<<<dim3(L_ / 64, SC / 64, B_), 256, 0, stream>>>(
          scores, stats, probsT, s0, S_, s0);
    } else {
      tdrop_kernel<<<dim3(L_ / 64, SC / 64, B_), 256, 0, stream>>>(
          scores, stats, probsT, s0, SC, 0);
      gemm2_mfma<<<dim3(L_ / 128, D_ / 128, B_), 256, 0, stream>>>(
          probsT, XT, out, SC, SC, s0, c > 0 ? 1 : 0);
    }
  }
  if (planA) {
    gemm2_mfma<<<dim3(L_ / 128, D_ / 128, B_), 256, 0, stream>>>(
        probsT, XT, out, S_, S_, 0, 0);
  }
}

// Round 3
// 598.981 us; speedup vs baseline: 2.0776x; 1.2240x over previous
//
#include <hip/hip_runtime.h>
#include <stdint.h>
#include <stddef.h>

// B=16, S=512, D=256, L=8192, DROP_P=0.2
#define B_ 16
#define S_ 512
#define D_ 256
#define L_ 8192

typedef unsigned short u16;
typedef _Float16 f16;
typedef f16 f16x4 __attribute__((ext_vector_type(4)));
typedef f16 f16x8 __attribute__((ext_vector_type(8)));   // MFMA A/B frag (4 VGPRs)
typedef float f32x4 __attribute__((ext_vector_type(4))); // MFMA C/D frag

// ---------------------------------------------------------------------------
// async global -> LDS, 16B/lane. LDS dest = wave-uniform base + lane*16.
// ---------------------------------------------------------------------------
__device__ __forceinline__ void gl16(const void* g, void* l) {
  __builtin_amdgcn_global_load_lds(
      (const __attribute__((address_space(1))) unsigned int*)g,
      (__attribute__((address_space(3))) unsigned int*)l, 16, 0, 0);
}

// ---------------------------------------------------------------------------
// JAX threefry2x32 dropout, key=(0,42), partitionable (bit-exact, r1-verified)
// ---------------------------------------------------------------------------
__device__ __forceinline__ uint32_t rotl32(uint32_t x, int r) {
  return (x << r) | (x >> (32 - r));
}
__device__ __forceinline__ bool drop_keep(uint32_t j) {
  const uint32_t k0 = 0u, k1 = 42u, k2 = 0x1BD11BDAu ^ k0 ^ k1;
  uint32_t v0 = 0u + k0;
  uint32_t v1 = j + k1;
#define TF_R(r) { v0 += v1; v1 = rotl32(v1, (r)); v1 ^= v0; }
  TF_R(13) TF_R(15) TF_R(26) TF_R(6)
  v0 += k1; v1 += k2 + 1u;
  TF_R(17) TF_R(29) TF_R(16) TF_R(24)
  v0 += k2; v1 += k0 + 2u;
  TF_R(13) TF_R(15) TF_R(26) TF_R(6)
  v0 += k0; v1 += k1 + 3u;
  TF_R(17) TF_R(29) TF_R(16) TF_R(24)
  v0 += k1; v1 += k2 + 4u;
  TF_R(13) TF_R(15) TF_R(26) TF_R(6)
  v0 += k2; v1 += k0 + 5u;
#undef TF_R
  uint32_t bits = v0 ^ v1;
  float u = __uint_as_float((bits >> 9) | 0x3f800000u) - 1.0f;
  return u < 0.8f;
}

// ---------------------------------------------------------------------------
// prep: fp32 -> fp16 convert (8 elem/thread)
// ---------------------------------------------------------------------------
__global__ __launch_bounds__(256)
void conv16_kernel(const float* __restrict__ src, f16* __restrict__ dst, int n) {
  int i = (blockIdx.x * 256 + threadIdx.x) * 8;
  if (i >= n) return;
  float4 a = *(const float4*)&src[i];
  float4 b = *(const float4*)&src[i + 4];
  f16x8 o;
  o[0] = (f16)a.x; o[1] = (f16)a.y; o[2] = (f16)a.z; o[3] = (f16)a.w;
  o[4] = (f16)b.x; o[5] = (f16)b.y; o[6] = (f16)b.z; o[7] = (f16)b.w;
  *(f16x8*)&dst[i] = o;
}

// x [B][S][D] fp32 -> xT [B][D][S] fp16
__global__ __launch_bounds__(256)
void xt16_kernel(const float* __restrict__ x, f16* __restrict__ xT) {
  const int b = blockIdx.z, sb = blockIdx.x * 32, db = blockIdx.y * 32;
  __shared__ float t[32][33];
  const int tid = threadIdx.x;
  const int r = tid >> 3, c4 = (tid & 7) * 4;
  float4 v = *(const float4*)&x[((size_t)b * S_ + sb + r) * D_ + db + c4];
  t[r][c4] = v.x; t[r][c4 + 1] = v.y; t[r][c4 + 2] = v.z; t[r][c4 + 3] = v.w;
  __syncthreads();
  const int dr = tid >> 3, s4 = (tid & 7) * 4;
  f16x4 o;
#pragma unroll
  for (int j = 0; j < 4; ++j) o[j] = (f16)t[s4 + j][dr];
  *(f16x4*)&xT[((size_t)b * D_ + db + dr) * S_ + sb + s4] = o;
}

// ---------------------------------------------------------------------------
// GEMM1 (fp16 MFMA, NT): scores[b, st.., lt..] = x[s,:] . E[l,:]  (fp32 out)
// 128x128 tile, BK=32. Epilogue: per-row tile max + expsum -> partials.
// ---------------------------------------------------------------------------
__global__ __launch_bounds__(256)
void gemm1_f16(const f16* __restrict__ xh, const f16* __restrict__ eh,
               float* __restrict__ scores, float2* __restrict__ partials,
               int s0, int sc) {
  __shared__ __align__(16) f16 As[128 * 32];
  __shared__ __align__(16) f16 Bs[128 * 32];
  __shared__ float pmaxA[128][2];
  __shared__ float psumA[128][2];

  const int tid = threadIdx.x;
  const int lane = tid & 63, wave = tid >> 6;
  const int b = blockIdx.z, lt = blockIdx.x * 128, st = blockIdx.y * 128;

  const int ra = wave * 32 + (lane >> 2);
  const int kc = (lane & 3) * 8;
  const size_t offA0 = ((size_t)b * S_ + s0 + st + ra) * D_ + kc;
  const size_t offA1 = offA0 + 16 * D_;
  const size_t offB0 = ((size_t)b * L_ + lt + ra) * D_ + kc;
  const size_t offB1 = offB0 + 16 * D_;
  const int lo0 = wave * 2048 + lane * 16;  // bytes

  const int lm = lane & 15, kq = lane >> 4;
  const int wm = (wave & 1) * 64, wn = (wave >> 1) * 64;

  f32x4 acc[4][4] = {};

  for (int k0 = 0; k0 < D_; k0 += 32) {
    __syncthreads();
    gl16(xh + offA0 + k0, (char*)As + lo0);
    gl16(xh + offA1 + k0, (char*)As + lo0 + 1024);
    gl16(eh + offB0 + k0, (char*)Bs + lo0);
    gl16(eh + offB1 + k0, (char*)Bs + lo0 + 1024);
    __syncthreads();

    f16x8 fa[4], fb[4];
#pragma unroll
    for (int mi = 0; mi < 4; ++mi)
      fa[mi] = *(const f16x8*)&As[(wm + mi * 16 + lm) * 32 + kq * 8];
#pragma unroll
    for (int ni = 0; ni < 4; ++ni)
      fb[ni] = *(const f16x8*)&Bs[(wn + ni * 16 + lm) * 32 + kq * 8];
#pragma unroll
    for (int mi = 0; mi < 4; ++mi)
#pragma unroll
      for (int ni = 0; ni < 4; ++ni)
        acc[mi][ni] = __builtin_amdgcn_mfma_f32_16x16x32_f16(
            fa[mi], fb[ni], acc[mi][ni], 0, 0, 0);
  }

  // ---- scores write. C/D: col = lane&15, row = (lane>>4)*4 + reg ----
#pragma unroll
  for (int mi = 0; mi < 4; ++mi)
#pragma unroll
    for (int ni = 0; ni < 4; ++ni) {
      const int m0 = wm + mi * 16 + kq * 4;
      const int n = wn + ni * 16 + lm;
      float* sp = scores + ((size_t)b * sc + st + m0) * L_ + lt + n;
#pragma unroll
      for (int r = 0; r < 4; ++r) sp[(size_t)r * L_] = acc[mi][ni][r];
    }

  // ---- per-row (token) partial max over this 128-col tile ----
  float cmax[4][4];
#pragma unroll
  for (int mi = 0; mi < 4; ++mi)
#pragma unroll
    for (int r = 0; r < 4; ++r) {
      float v = acc[mi][0][r];
      v = fmaxf(v, acc[mi][1][r]);
      v = fmaxf(v, acc[mi][2][r]);
      cmax[mi][r] = fmaxf(v, acc[mi][3][r]);
    }
#pragma unroll
  for (int off = 1; off < 16; off <<= 1)
#pragma unroll
    for (int mi = 0; mi < 4; ++mi)
#pragma unroll
      for (int r = 0; r < 4; ++r)
        cmax[mi][r] = fmaxf(cmax[mi][r], __shfl_xor(cmax[mi][r], off, 64));
  if (lm == 0) {
#pragma unroll
    for (int mi = 0; mi < 4; ++mi)
#pragma unroll
      for (int r = 0; r < 4; ++r)
        pmaxA[wm + mi * 16 + kq * 4 + r][wave >> 1] = cmax[mi][r];
  }
  __syncthreads();
  float rowm[4][4];
#pragma unroll
  for (int mi = 0; mi < 4; ++mi)
#pragma unroll
    for (int r = 0; r < 4; ++r) {
      int row = wm + mi * 16 + kq * 4 + r;
      rowm[mi][r] = fmaxf(pmaxA[row][0], pmaxA[row][1]);
    }
  float psum[4][4] = {};
#pragma unroll
  for (int mi = 0; mi < 4; ++mi)
#pragma unroll
    for (int ni = 0; ni < 4; ++ni)
#pragma unroll
      for (int r = 0; r < 4; ++r)
        psum[mi][r] += __expf(acc[mi][ni][r] - rowm[mi][r]);
#pragma unroll
  for (int off = 1; off < 16; off <<= 1)
#pragma unroll
    for (int mi = 0; mi < 4; ++mi)
#pragma unroll
      for (int r = 0; r < 4; ++r)
        psum[mi][r] += __shfl_xor(psum[mi][r], off, 64);
  if (lm == 0) {
#pragma unroll
    for (int mi = 0; mi < 4; ++mi)
#pragma unroll
      for (int r = 0; r < 4; ++r)
        psumA[wm + mi * 16 + kq * 4 + r][wave >> 1] = psum[mi][r];
  }
  __syncthreads();
  if (tid < 128) {
    float m = fmaxf(pmaxA[tid][0], pmaxA[tid][1]);
    float Z = psumA[tid][0] + psumA[tid][1];
    partials[((size_t)b * 64 + blockIdx.x) * sc + st + tid] = make_float2(m, Z);
  }
}

// ---------------------------------------------------------------------------
// combine partial (m,Z) over 64 l-tiles -> stats (m, factor)
// ---------------------------------------------------------------------------
__global__ __launch_bounds__(256)
void combine_kernel(const float2* __restrict__ partials,
                    const int* __restrict__ mask, float2* __restrict__ stats,
                    int s0, int sc) {
  const int idx = blockIdx.x * 256 + threadIdx.x;  // b*sc + si
  const int b = idx / sc, si = idx - b * sc;
  float m = -3.402823466e38f, Z = 0.f;
  for (int t = 0; t < 64; ++t) {
    float2 p = partials[((size_t)b * 64 + t) * sc + si];
    if (p.x > m) {
      Z = Z * __expf(m - p.x) + p.y;
      m = p.x;
    } else {
      Z += p.y * __expf(p.x - m);
    }
  }
  float f = (mask[b * S_ + s0 + si] != 0) ? (1.25f / Z) : 0.0f;
  stats[idx] = make_float2(m, f);
}

// ---------------------------------------------------------------------------
// transpose + normalize + dropout: scores fp32 [b][sc][L] ->
// probsT fp16 [b][L][S_] (s-offset s0)
// ---------------------------------------------------------------------------
__global__ __launch_bounds__(256)
void tdrop_kernel(const float* __restrict__ scores,
                  const float2* __restrict__ stats, f16* __restrict__ probsT,
                  int s0, int sc) {
  const int b = blockIdx.z, lt = blockIdx.x * 64, st = blockIdx.y * 64;
  const int tid = threadIdx.x;
  __shared__ float T[64][65];

  const int r0 = tid >> 4, c0 = (tid & 15) * 4;
#pragma unroll
  for (int p = 0; p < 4; ++p) {
    int r = p * 16 + r0;
    float4 v = *(const float4*)&scores[((size_t)b * sc + st + r) * L_ + lt + c0];
    T[r][c0] = v.x; T[r][c0 + 1] = v.y; T[r][c0 + 2] = v.z; T[r][c0 + 3] = v.w;
  }
  __syncthreads();

  const int sb = (tid & 7) * 8;
#pragma unroll
  for (int p = 0; p < 2; ++p) {
    int ll = p * 32 + (tid >> 3);
    f16x8 o;
#pragma unroll
    for (int j = 0; j < 8; ++j) {
      int s_loc = st + sb + j;
      float2 mf = stats[b * sc + s_loc];
      float pv = __expf(T[sb + j][ll] - mf.x) * mf.y;
      uint32_t gidx =
          ((uint32_t)(b * S_ + s0 + s_loc)) * (uint32_t)L_ + (uint32_t)(lt + ll);
      o[j] = drop_keep(gidx) ? (f16)pv : (f16)0.f;
    }
    *(f16x8*)&probsT[((size_t)b * L_ + lt + ll) * S_ + s0 + st + sb] = o;
  }
}

// ---------------------------------------------------------------------------
// GEMM2 (fp16 MFMA, NT, full-D tile): out[b, lt..+127, 0..255] =
//   probsT[l,:] . xT[d,:], K = 512
// ---------------------------------------------------------------------------
__global__ __launch_bounds__(256)
void gemm2_f16(const f16* __restrict__ pT, const f16* __restrict__ xT,
               float* __restrict__ out) {
  __shared__ __align__(16) f16 As[128 * 32];  // 8 KB
  __shared__ __align__(16) f16 Bs[256 * 32];  // 16 KB

  const int tid = threadIdx.x;
  const int lane = tid & 63, wave = tid >> 6;
  const int b = blockIdx.z, lt = blockIdx.x * 128;

  const int kc = (lane & 3) * 8;
  const size_t offA0 = ((size_t)b * L_ + lt + wave * 32 + (lane >> 2)) * S_ + kc;
  const size_t offA1 = offA0 + 16 * S_;
  const size_t offB = ((size_t)b * D_ + wave * 64 + (lane >> 2)) * S_ + kc;
  const int loA = wave * 2048 + lane * 16;  // bytes
  const int loB = wave * 4096 + lane * 16;

  const int lm = lane & 15, kq = lane >> 4;
  const int wm = (wave & 1) * 64, wn = (wave >> 1) * 128;

  f32x4 acc[4][8] = {};

  for (int k0 = 0; k0 < S_; k0 += 32) {
    __syncthreads();
    gl16(pT + offA0 + k0, (char*)As + loA);
    gl16(pT + offA1 + k0, (char*)As + loA + 1024);
#pragma unroll
    for (int i = 0; i < 4; ++i)
      gl16(xT + offB + (size_t)i * 16 * S_ + k0, (char*)Bs + loB + i * 1024);
    __syncthreads();

    f16x8 fa[4], fb[8];
#pragma unroll
    for (int mi = 0; mi < 4; ++mi)
      fa[mi] = *(const f16x8*)&As[(wm + mi * 16 + lm) * 32 + kq * 8];
#pragma unroll
    for (int ni = 0; ni < 8; ++ni)
      fb[ni] = *(const f16x8*)&Bs[(wn + ni * 16 + lm) * 32 + kq * 8];
#pragma unroll
    for (int mi = 0; mi < 4; ++mi)
#pragma unroll
      for (int ni = 0; ni < 8; ++ni)
        acc[mi][ni] = __builtin_amdgcn_mfma_f32_16x16x32_f16(
            fa[mi], fb[ni], acc[mi][ni], 0, 0, 0);
  }

#pragma unroll
  for (int mi = 0; mi < 4; ++mi)
#pragma unroll
    for (int ni = 0; ni < 8; ++ni) {
      const int m0 = wm + mi * 16 + kq * 4;
      const int n = wn + ni * 16 + lm;
      float* op = out + ((size_t)b * L_ + lt + m0) * D_ + n;
#pragma unroll
      for (int r = 0; r < 4; ++r) op[(size_t)r * D_] = acc[mi][ni][r];
    }
}

// ---------------------------------------------------------------------------
extern "C" void kernel_launch(void* const* d_in, const int* in_sizes, int n_in,
                              void* d_out, int out_size, void* d_ws, size_t ws_size,
                              hipStream_t stream) {
  const float* x = (const float*)d_in[0];
  const int* mask = (const int*)d_in[1];
  const float* E = (const float*)d_in[2];
  float* out = (float*)d_out;

  char* ws = (char*)d_ws;
  const size_t nE = (size_t)B_ * L_ * D_;  // 33.5M
  const size_t nX = (size_t)B_ * S_ * D_;  // 2.1M
  size_t o = 0;
  f16* Eh = (f16*)(ws + o); o += nE * 2;                      // 64 MB
  f16* Xh = (f16*)(ws + o); o += nX * 2;                      // 4 MB
  f16* XT = (f16*)(ws + o); o += nX * 2;                      // 4 MB
  float2* stats = (float2*)(ws + o); o += (size_t)B_ * 512 * 8;      // 64 KB
  float2* partials = (float2*)(ws + o); o += (size_t)B_ * 64 * 512 * 8;  // 4 MB
  // scores [B][sc][L] fp32 then probsT [B][L][S] fp16
  const size_t need512 =
      o + (size_t)B_ * 512 * L_ * 4 + (size_t)B_ * L_ * S_ * 2;  // ~478 MB
  const int sc = (ws_size >= need512) ? 512 : 128;
  float* scores = (float*)(ws + o);
  f16* probsT = (f16*)(ws + o + (size_t)B_ * sc * L_ * 4);

  conv16_kernel<<<dim3((unsigned)(nE / 8 / 256)), 256, 0, stream>>>(E, Eh, (int)nE);
  conv16_kernel<<<dim3((unsigned)(nX / 8 / 256)), 256, 0, stream>>>(x, Xh, (int)nX);
  xt16_kernel<<<dim3(S_ / 32, D_ / 32, B_), 256, 0, stream>>>(x, XT);

  const int nch = S_ / sc;
  for (int c = 0; c < nch; ++c) {
    const int s0 = c * sc;
    gemm1_f16<<<dim3(L_ / 128, sc / 128, B_), 256, 0, stream>>>(
        Xh, Eh, scores, partials, s0, sc);
    combine_kernel<<<dim3(B_ * sc / 256), 256, 0, stream>>>(partials, mask,
                                                            stats, s0, sc);
    tdrop_kernel<<<dim3(L_ / 64, sc / 64, B_), 256, 0, stream>>>(
        scores, stats, probsT, s0, sc);
  }
  gemm2_f16<<<dim3(L_ / 128, 1, B_), 256, 0, stream>>>(probsT, XT, out);
}